// Round 5
// baseline (186.071 us; speedup 1.0000x reference)
//

#include <hip/hip_runtime.h>
#include <hip/hip_bf16.h>
#include <math.h>

// ArcFace forward: out = S * modified, where modified == logits except at
// (row, label): cos(arccos(t) + MARGIN) = t*cos(m) - sqrt(1-t^2)*sin(m).
//
// R4 post-mortem: "8 loads in flight" never happened — VGPR_Count=24 proves
// the regalloc collapsed the batch into load/store pairs; dur stuck at 61us.
// R5: (a) explicit software pipeline: load batch k+1 (4 float4s) BEFORE
// storing batch k -> always ~4KB in flight per thread, ~40 VGPRs live;
// (b) 1250 blocks x 256 thr x 20 float4s exact cover -> all blocks
// co-resident (no ramp/tail), long-lived waves like the 6.7 TB/s fill kernel;
// (c) plain stores (fillBufferAligned hits 6.7 TB/s with plain stores;
// in+out = 200MB fits the 256MB L3).

#define ARC_S      64.0f
#define COS_M      0.8775825618903728f   // cos(0.5)
#define SIN_M      0.4794255386042030f   // sin(0.5)

typedef float floatx4 __attribute__((ext_vector_type(4)));

#define T_PER_BLK   256
#define F4_PER_THR  20                   // 5 batches of 4
#define F4_PER_BLK  (T_PER_BLK * F4_PER_THR)   // 5120 float4s = 80 KB

__global__ __launch_bounds__(256) void scale_copy_kernel(
    const floatx4* __restrict__ in,
    floatx4*       __restrict__ out)
{
    const size_t base = (size_t)blockIdx.x * F4_PER_BLK + threadIdx.x;
    const floatx4* __restrict__ p = in  + base;
    floatx4*       __restrict__ q = out + base;

    floatx4 cur[4];
    #pragma unroll
    for (int j = 0; j < 4; ++j)
        cur[j] = p[j * T_PER_BLK];

    #pragma unroll
    for (int k = 1; k < 5; ++k) {
        floatx4 nxt[4];
        #pragma unroll
        for (int j = 0; j < 4; ++j)              // batch k in flight...
            nxt[j] = p[(k * 4 + j) * T_PER_BLK];
        #pragma unroll
        for (int j = 0; j < 4; ++j)              // ...while batch k-1 stores
            q[((k - 1) * 4 + j) * T_PER_BLK] = cur[j] * ARC_S;
        #pragma unroll
        for (int j = 0; j < 4; ++j)
            cur[j] = nxt[j];
    }

    #pragma unroll
    for (int j = 0; j < 4; ++j)
        q[(16 + j) * T_PER_BLK] = cur[j] * ARC_S;
}

// Handles (1) the 256 target-element fixups, (2) any flat tail not covered
// by full block chunks (empty for 256x100000).
__global__ __launch_bounds__(256) void fixup_kernel(
    const float* __restrict__ logits,
    const int*   __restrict__ labels,
    float*       __restrict__ out,
    int B, int C, size_t tailStart, size_t total)
{
    const int t = threadIdx.x;

    if (t < B) {
        const int lbl = labels[t];
        if (lbl >= 0 && lbl < C) {
            const size_t idx = (size_t)t * (size_t)C + (size_t)lbl;
            const float x = logits[idx];
            const float s = sqrtf(fmaxf(0.0f, 1.0f - x * x));
            out[idx] = ARC_S * (x * COS_M - s * SIN_M);
        }
    }

    for (size_t i = tailStart + t; i < total; i += 256)
        out[i] = ARC_S * logits[i];
}

extern "C" void kernel_launch(void* const* d_in, const int* in_sizes, int n_in,
                              void* d_out, int out_size, void* d_ws, size_t ws_size,
                              hipStream_t stream) {
    const float* logits = (const float*)d_in[0];
    const int*   labels = (const int*)d_in[1];
    float*       out    = (float*)d_out;

    const int B = in_sizes[1];                 // 256
    const int C = in_sizes[0] / B;             // 100000
    const size_t total  = (size_t)B * (size_t)C;        // 25.6e6 floats
    const size_t total4 = total / 4;                    // 6.4e6 float4s
    const int    nBlocks = (int)(total4 / F4_PER_BLK);  // 1250 full chunks
    const size_t tailStart = (size_t)nBlocks * F4_PER_BLK * 4u;  // == total

    scale_copy_kernel<<<dim3(nBlocks), dim3(T_PER_BLK), 0, stream>>>(
        (const floatx4*)logits, (floatx4*)out);
    fixup_kernel<<<dim3(1), dim3(256), 0, stream>>>(
        logits, labels, out, B, C, tailStart, total);
}
